// Round 4
// baseline (516.205 us; speedup 1.0000x reference)
//
#include <hip/hip_runtime.h>
#include <hip/hip_bf16.h>

// Problem: B=32, T=2048, C=1152, O=29.
// z[b,o] = ( (1/64)*dot(W[o,:], s[b,:]) - 2*T*sum(W[o,:]) + T*bias[o] ) / length[b]
// where s[b,c] = sum_t x[b,t,c].
//
// Single fused kernel (split-K finisher): each block sums a 32-row T-slab of x
// into part[p][b][:]; the last block to finish for batch b (agent-scope
// counter) reduces the TSPLIT partials in LDS and emits the 29 projections.

#define PB 32
#define PT 2048
#define PC 1152
#define PO 29
#define TSPLIT 64
#define SLAB (PT / TSPLIT)   // 32 rows per block
#define C4 (PC / 4)          // 288 float4 per row

typedef float f32x4 __attribute__((ext_vector_type(4)));

// grid = (B, TSPLIT), block = 256 (4 waves).
__global__ __launch_bounds__(256) void fused_kernel(const float* __restrict__ x,
                                                    float* __restrict__ part,
                                                    unsigned int* __restrict__ counters,
                                                    const float* __restrict__ W,
                                                    const float* __restrict__ bias,
                                                    const int* __restrict__ length,
                                                    float* __restrict__ out) {
    const int b   = blockIdx.x;
    const int p   = blockIdx.y;
    const int tid = threadIdx.x;

    // ---- Phase 1: stream a 147 KB slab, coalesced nt dwordx4 loads ----
    const f32x4* x4 = (const f32x4*)(x + (size_t)b * PT * PC)
                    + (size_t)(p * SLAB) * C4;

    f32x4 a0 = (f32x4)(0.f);
    f32x4 a1 = (f32x4)(0.f);

#pragma unroll 8
    for (int t = 0; t < SLAB; ++t) {
        const f32x4* row = x4 + (size_t)t * C4;
        a0 += __builtin_nontemporal_load(&row[tid]);
        if (tid < C4 - 256) {
            a1 += __builtin_nontemporal_load(&row[256 + tid]);
        }
    }

    f32x4* out4 = (f32x4*)(part + ((size_t)p * PB + b) * PC);
    out4[tid] = a0;
    if (tid < C4 - 256) out4[256 + tid] = a1;

    // ---- Publish: am I the last block for this b? ----
    __shared__ int is_last;
    __syncthreads();   // s_waitcnt vmcnt(0): all partial stores at least in L2
    if (tid == 0) {
        // ACQ_REL agent-scope atomic: release flushes this XCD's L2 (partials
        // become visible device-wide); acquire orders the counter read.
        unsigned int old = __hip_atomic_fetch_add(&counters[b], 1u,
                                                  __ATOMIC_ACQ_REL,
                                                  __HIP_MEMORY_SCOPE_AGENT);
        is_last = (old == TSPLIT - 1);
    }
    __syncthreads();
    if (!is_last) return;

    // ---- Phase 2 (one block per b): reduce partials, project ----
    __threadfence();   // acquire: invalidate potentially-stale L2/L1 lines

    __shared__ float s[PC];
    const f32x4* part4 = (const f32x4*)part;
    for (int c4 = tid; c4 < C4; c4 += 256) {
        f32x4 acc = (f32x4)(0.f);
#pragma unroll 8
        for (int pp = 0; pp < TSPLIT; ++pp) {
            acc += part4[((size_t)pp * PB + b) * C4 + c4];
        }
        ((f32x4*)s)[c4] = acc;
    }
    __syncthreads();

    const int wave = tid >> 6;
    const int lane = tid & 63;
    const float invlen = 1.0f / (float)length[b];

    for (int o = wave; o < PO; o += 4) {
        const float* Wo = W + o * PC;
        float dot = 0.f, wsum = 0.f;
#pragma unroll
        for (int c = lane; c < PC; c += 64) {
            float w = Wo[c];
            dot  += w * s[c];
            wsum += w;
        }
#pragma unroll
        for (int off = 32; off > 0; off >>= 1) {
            dot  += __shfl_down(dot,  off);
            wsum += __shfl_down(wsum, off);
        }
        if (lane == 0) {
            float z = dot * (1.0f / 64.0f)
                    - 2.0f * (float)PT * wsum
                    + (float)PT * bias[o];
            out[b * PO + o] = z * invlen;
        }
    }
}

extern "C" void kernel_launch(void* const* d_in, const int* in_sizes, int n_in,
                              void* d_out, int out_size, void* d_ws, size_t ws_size,
                              hipStream_t stream) {
    const float* x      = (const float*)d_in[0];
    const int*   length = (const int*)d_in[1];
    const float* W      = (const float*)d_in[2];
    const float* bias   = (const float*)d_in[3];
    float*       out    = (float*)d_out;

    float*        part     = (float*)d_ws;                       // [TSPLIT,B,C] = 9.4 MB
    unsigned int* counters = (unsigned int*)((char*)d_ws + (size_t)TSPLIT * PB * PC * sizeof(float));

    // ws is poisoned to 0xAA before every timed call — zero only the counters.
    hipMemsetAsync(counters, 0, PB * sizeof(unsigned int), stream);

    dim3 g(PB, TSPLIT);
    fused_kernel<<<g, 256, 0, stream>>>(x, part, counters, W, bias, length, out);
}

// Round 5
// 460.798 us; speedup vs baseline: 1.1202x; 1.1202x over previous
//
#include <hip/hip_runtime.h>
#include <hip/hip_bf16.h>

// Problem: B=32, T=2048, C=1152, O=29.
// z[b,o] = ( (1/64)*dot(W[o,:], s[b,:]) - 2*T*sum(W[o,:]) + T*bias[o] ) / length[b]
// where s[b,c] = sum_t x[b,t,c].
//
// Two deterministic kernels (no memset, no atomics — the R4 fused/atomic
// variant regressed due to per-block L2 writeback/invalidate):
//   K1: part[p][b][c] = sum over T-slab p of x[b,t,c]   (streams all of x once)
//   K2: per-b block: s[c] = sum_p part[p][b][c] (LDS), then 29 projections.
//
// K1 design notes (R5): 320-thread blocks, threads 0..287 each own exactly one
// f32x4 column of the slab -> NO divergence inside the hot loop, two
// independent accumulator chains, unroll 8 (16 loads in flight). Plain loads
// (no nt) so the L3-resident portion of x (warm from the harness restore
// copy) is served from Infinity Cache.

#define PB 32
#define PT 2048
#define PC 1152
#define PO 29
#define TSPLIT 64
#define SLAB (PT / TSPLIT)   // 32 rows per block
#define C4 (PC / 4)          // 288 float4 per row

typedef float f32x4 __attribute__((ext_vector_type(4)));

// grid = (B, TSPLIT), block = 320 (5 waves; lanes 288..319 idle by design).
__global__ __launch_bounds__(320) void sum_t_kernel(const float* __restrict__ x,
                                                    float* __restrict__ part) {
    const int b   = blockIdx.x;
    const int p   = blockIdx.y;
    const int tid = threadIdx.x;

    if (tid < C4) {
        const f32x4* base = (const f32x4*)(x + (size_t)b * PT * PC)
                          + (size_t)(p * SLAB) * C4 + tid;

        f32x4 a0 = (f32x4)(0.f);
        f32x4 a1 = (f32x4)(0.f);

#pragma unroll 8
        for (int t = 0; t < SLAB; t += 2) {
            a0 += base[(size_t)t * C4];        // even rows
            a1 += base[(size_t)(t + 1) * C4];  // odd rows (independent chain)
        }

        ((f32x4*)(part + ((size_t)p * PB + b) * PC))[tid] = a0 + a1;
    }
}

// grid = B, block = 256 (4 waves). Stage 1: reduce TSPLIT partials into LDS s[].
// Stage 2: each wave handles o = wave, wave+4, ... ; shuffle-reduce dot & wsum.
__global__ __launch_bounds__(256) void reduce_proj_kernel(const float* __restrict__ part,
                                                          const float* __restrict__ W,
                                                          const float* __restrict__ bias,
                                                          const int* __restrict__ length,
                                                          float* __restrict__ out) {
    __shared__ float s[PC];
    const int b   = blockIdx.x;
    const int tid = threadIdx.x;

    const f32x4* part4 = (const f32x4*)part;
    for (int c4 = tid; c4 < C4; c4 += 256) {
        f32x4 acc = (f32x4)(0.f);
#pragma unroll 8
        for (int p = 0; p < TSPLIT; ++p) {
            acc += part4[((size_t)p * PB + b) * C4 + c4];
        }
        ((f32x4*)s)[c4] = acc;
    }
    __syncthreads();

    const int wave = tid >> 6;
    const int lane = tid & 63;
    const float invlen = 1.0f / (float)length[b];

    for (int o = wave; o < PO; o += 4) {
        const float* Wo = W + o * PC;
        float dot = 0.f, wsum = 0.f;
#pragma unroll
        for (int c = lane; c < PC; c += 64) {
            float w = Wo[c];
            dot  += w * s[c];
            wsum += w;
        }
#pragma unroll
        for (int off = 32; off > 0; off >>= 1) {
            dot  += __shfl_down(dot,  off);
            wsum += __shfl_down(wsum, off);
        }
        if (lane == 0) {
            float z = dot * (1.0f / 64.0f)
                    - 2.0f * (float)PT * wsum
                    + (float)PT * bias[o];
            out[b * PO + o] = z * invlen;
        }
    }
}

extern "C" void kernel_launch(void* const* d_in, const int* in_sizes, int n_in,
                              void* d_out, int out_size, void* d_ws, size_t ws_size,
                              hipStream_t stream) {
    const float* x      = (const float*)d_in[0];
    const int*   length = (const int*)d_in[1];
    const float* W      = (const float*)d_in[2];
    const float* bias   = (const float*)d_in[3];
    float*       out    = (float*)d_out;
    float*       part   = (float*)d_ws;   // [TSPLIT, B, C] partials (9.4 MB)

    dim3 g1(PB, TSPLIT);
    sum_t_kernel<<<g1, 320, 0, stream>>>(x, part);

    reduce_proj_kernel<<<PB, 256, 0, stream>>>(part, W, bias, length, out);
}

// Round 6
// 458.970 us; speedup vs baseline: 1.1247x; 1.0040x over previous
//
#include <hip/hip_runtime.h>
#include <hip/hip_bf16.h>

// Problem: B=32, T=2048, C=1152, O=29.
// z[b,o] = ( (1/64)*dot(W[o,:], s[b,:]) - 2*T*sum(W[o,:]) + T*bias[o] ) / length[b]
// where s[b,c] = sum_t x[b,t,c].
//
// R6: attack the observed 1.55 TB/s streaming ceiling (R4 counters) with
//  (a) dense read front: block (b,j) reads rows j, j+64, ... of batch b, so
//      the 64 blocks per batch sweep the batch as one contiguous front
//      (DRAM row-buffer locality), instead of 2048 private slab pointers;
//  (b) deep MLP: fully unrolled 32-load body, 4 independent accumulator
//      chains -> compiler must hold many f32x4 loads in flight (VGPR ~128).

#define PB 32
#define PT 2048
#define PC 1152
#define PO 29
#define JSPLIT 64            // blocks per batch; also the row stride
#define KROWS (PT / JSPLIT)  // 32 rows per block
#define C4 (PC / 4)          // 288 f32x4 per row

typedef float f32x4 __attribute__((ext_vector_type(4)));

// grid = (B, JSPLIT), block = 320 (lanes 288..319 idle; no in-loop divergence).
__global__ __launch_bounds__(320) void sum_t_kernel(const float* __restrict__ x,
                                                    float* __restrict__ part) {
    const int b   = blockIdx.x;
    const int j   = blockIdx.y;
    const int tid = threadIdx.x;
    if (tid >= C4) return;   // no barriers in this kernel — early exit is safe

    const f32x4* p0 = (const f32x4*)(x + (size_t)b * PT * PC)
                    + (size_t)j * C4 + tid;
    const size_t STR = (size_t)JSPLIT * C4;   // 64 rows = 294912 B

    f32x4 a0 = (f32x4)(0.f), a1 = a0, a2 = a0, a3 = a0;
#pragma unroll
    for (int k = 0; k < KROWS; k += 4) {
        a0 += p0[(size_t)(k + 0) * STR];
        a1 += p0[(size_t)(k + 1) * STR];
        a2 += p0[(size_t)(k + 2) * STR];
        a3 += p0[(size_t)(k + 3) * STR];
    }

    ((f32x4*)(part + ((size_t)j * PB + b) * PC))[tid] = (a0 + a1) + (a2 + a3);
}

// grid = B, block = 256 (4 waves). Stage 1: reduce JSPLIT partials into LDS s[].
// Stage 2: each wave handles o = wave, wave+4, ... ; shuffle-reduce dot & wsum.
__global__ __launch_bounds__(256) void reduce_proj_kernel(const float* __restrict__ part,
                                                          const float* __restrict__ W,
                                                          const float* __restrict__ bias,
                                                          const int* __restrict__ length,
                                                          float* __restrict__ out) {
    __shared__ float s[PC];
    const int b   = blockIdx.x;
    const int tid = threadIdx.x;

    const f32x4* part4 = (const f32x4*)part;
    for (int c4 = tid; c4 < C4; c4 += 256) {
        f32x4 acc = (f32x4)(0.f);
#pragma unroll 8
        for (int p = 0; p < JSPLIT; ++p) {
            acc += part4[((size_t)p * PB + b) * C4 + c4];
        }
        ((f32x4*)s)[c4] = acc;
    }
    __syncthreads();

    const int wave = tid >> 6;
    const int lane = tid & 63;
    const float invlen = 1.0f / (float)length[b];

    for (int o = wave; o < PO; o += 4) {
        const float* Wo = W + o * PC;
        float dot = 0.f, wsum = 0.f;
#pragma unroll
        for (int c = lane; c < PC; c += 64) {
            float w = Wo[c];
            dot  += w * s[c];
            wsum += w;
        }
#pragma unroll
        for (int off = 32; off > 0; off >>= 1) {
            dot  += __shfl_down(dot,  off);
            wsum += __shfl_down(wsum, off);
        }
        if (lane == 0) {
            float z = dot * (1.0f / 64.0f)
                    - 2.0f * (float)PT * wsum
                    + (float)PT * bias[o];
            out[b * PO + o] = z * invlen;
        }
    }
}

extern "C" void kernel_launch(void* const* d_in, const int* in_sizes, int n_in,
                              void* d_out, int out_size, void* d_ws, size_t ws_size,
                              hipStream_t stream) {
    const float* x      = (const float*)d_in[0];
    const int*   length = (const int*)d_in[1];
    const float* W      = (const float*)d_in[2];
    const float* bias   = (const float*)d_in[3];
    float*       out    = (float*)d_out;
    float*       part   = (float*)d_ws;   // [JSPLIT, B, C] partials (9.4 MB)

    dim3 g1(PB, JSPLIT);
    sum_t_kernel<<<g1, 320, 0, stream>>>(x, part);

    reduce_proj_kernel<<<PB, 256, 0, stream>>>(part, W, bias, length, out);
}